// Round 3
// baseline (76.351 us; speedup 1.0000x reference)
//
#include <hip/hip_runtime.h>
#include <hip/hip_cooperative_groups.h>
#include <math.h>

namespace cg = cooperative_groups;

#define NB   4
#define NS   1024
#define DIN  256
#define DOUT 64
#define NQ   128
#define NK   6
#define NROW (NB*NS)        // 4096
#define NF   (NQ*NK*2)      // 1536 features per row
#define ROWS 16             // rows per block
#define NBLK (NROW/ROWS)    // 256 blocks (1 per CU -> cooperative-safe)
#define THR  1024           // 16 waves per block

typedef __attribute__((ext_vector_type(8))) short  short8;
typedef __attribute__((ext_vector_type(4))) float  f32x4;

__device__ __forceinline__ unsigned short f2bf(float x) {
    unsigned int u = __float_as_uint(x);
    u = (u + 0x7fffu + ((u >> 16) & 1u)) >> 16;   // RNE
    return (unsigned short)u;
}

// ---------------------------------------------------------------------------
// Single cooperative kernel.
//   phase W (192 thr/block): W2T[d][f] bf16 slice -> global ws (overlapped)
//   phase 1: stage X0[16][256] fp32 into LDS
//   phase 2: angle[16][128] fp32 VALU GEMM (precision-critical)
//   phase 3: features -> bf16 LDS (XOR-swizzled), f=(k*2+c)*NQ+q
//   grid.sync()  (W2T now globally visible)
//   phase 4: MFMA V[16][64] = F[16][1536] x W2T^T, 16 waves = 4 dt x 4 kq,
//            f32x4 partials reduced via LDS
// ---------------------------------------------------------------------------
__global__ __launch_bounds__(THR, 4) void k_all(const float* __restrict__ X0,
                                                const float* __restrict__ tvec,
                                                const float* __restrict__ Wcw,
                                                const float* __restrict__ Wcb,
                                                const float* __restrict__ wq,
                                                const float* __restrict__ A,
                                                const float* __restrict__ Bp,
                                                unsigned short* __restrict__ W2T,
                                                float* __restrict__ V) {
    __shared__ char  smem[ROWS * NF * 2];         // 48 KiB: X0 stage, then F
    __shared__ f32x4 red[4][4][64];               // 16 KiB: kq-partial reduce
    const int row0 = blockIdx.x * ROWS;
    const int tid  = threadIdx.x;

    // ---- phase W: this block's 192-entry W2T slice (overlaps phases 1-3) --
    if (tid < 192) {
        int e   = blockIdx.x * 192 + tid;         // [0, DOUT*NQ*NK)
        int d   = e / (NQ * NK);
        int rem = e - d * (NQ * NK);              // q*NK + k
        int q   = rem / NK;
        int k   = rem - q * NK;
        float a  = A[e];
        float bp = Bp[e];
        float sb, cb;
        __sincosf(bp, &sb, &cb);
        W2T[(size_t)d * NF + (k * 2 + 0) * NQ + q] = f2bf(a * cb);
        W2T[(size_t)d * NF + (k * 2 + 1) * NQ + q] = f2bf(a * sb);
    }

    // ---- phase 1: stage X0 tile (16 KiB, 1 float4/thread) -----------------
    {
        const float4* src = (const float4*)(X0 + (size_t)row0 * DIN);
        ((float4*)smem)[tid] = src[tid];
    }
    __syncthreads();

    // ---- phase 2: angles (fp32) -------------------------------------------
    // thread (q = tid&127, hh = tid>>7) owns rows hh*2, hh*2+1
    const int q  = tid & 127;
    const int hh = tid >> 7;                      // 0..7
    const float* Xs = (const float*)smem;

    float4 acc0 = make_float4(0.f, 0.f, 0.f, 0.f);
    float4 acc1 = make_float4(0.f, 0.f, 0.f, 0.f);
    const float4* wrow = (const float4*)(Wcw + (size_t)q * DIN);
    #pragma unroll 8
    for (int i = 0; i < DIN / 4; ++i) {
        float4 wv = wrow[i];
        float4 x0 = *(const float4*)&Xs[(hh * 2    ) * DIN + i * 4];
        float4 x1 = *(const float4*)&Xs[(hh * 2 + 1) * DIN + i * 4];
        acc0.x += wv.x * x0.x; acc0.y += wv.y * x0.y;
        acc0.z += wv.z * x0.z; acc0.w += wv.w * x0.w;
        acc1.x += wv.x * x1.x; acc1.y += wv.y * x1.y;
        acc1.z += wv.z * x1.z; acc1.w += wv.w * x1.w;
    }
    const int   b    = row0 >> 10;                // 1024 rows per batch
    const float bias = Wcb[q] + wq[q] * tvec[b];
    float ang0 = (acc0.x + acc0.y) + (acc0.z + acc0.w) + bias;
    float ang1 = (acc1.x + acc1.y) + (acc1.z + acc1.w) + bias;

    __syncthreads();                              // done reading Xs

    // ---- phase 3: features -> bf16 LDS, row-XOR swizzle -------------------
    #pragma unroll
    for (int rr = 0; rr < 2; ++rr) {
        const int   row = hh * 2 + rr;
        const int   sw  = (row & 7) << 4;
        const float a   = rr ? ang1 : ang0;
        char* base = smem + row * (NF * 2);
        float s1, c1;
        __sincosf(a, &s1, &c1);
        float sk = s1, ck = c1;
        *(unsigned short*)(base + (((0 * NQ + q) * 2) ^ sw)) = f2bf(sk);
        *(unsigned short*)(base + (((1 * NQ + q) * 2) ^ sw)) = f2bf(ck);
        #pragma unroll
        for (int k = 1; k < NK; ++k) {
            float sn = sk * c1 + ck * s1;         // sin((k+1)a)
            float cn = ck * c1 - sk * s1;         // cos((k+1)a)
            *(unsigned short*)(base + ((((k * 2 + 0) * NQ + q) * 2) ^ sw)) = f2bf(sn);
            *(unsigned short*)(base + ((((k * 2 + 1) * NQ + q) * 2) ^ sw)) = f2bf(cn);
            sk = sn; ck = cn;
        }
    }

    // ---- grid-wide sync: features (block) + W2T (grid) --------------------
    cg::this_grid().sync();

    // ---- phase 4: MFMA, wave w -> (dt = w&3, kq = w>>2) --------------------
    const int w    = tid >> 6;
    const int lane = tid & 63;
    const int dt   = w & 3;                       // d-tile
    const int kq   = w >> 2;                      // K-quarter (384 each)
    const int arow = lane & 15;
    const int kgrp = lane >> 4;
    const int asw  = (arow & 7) << 4;

    f32x4 cacc = {0.f, 0.f, 0.f, 0.f};
    const unsigned short* wbase =
        W2T + (size_t)(dt * 16 + (lane & 15)) * NF + kgrp * 8;

    #pragma unroll 4
    for (int kk = 0; kk < NF / 4; kk += 32) {
        const int k0 = kq * (NF / 4) + kk;
        int aoff = (arow * (NF * 2) + (k0 + kgrp * 8) * 2) ^ asw;
        short8 afrag = *(const short8*)(smem + aoff);
        short8 bfrag = *(const short8*)(wbase + k0);
        cacc = __builtin_amdgcn_mfma_f32_16x16x32_bf16(afrag, bfrag, cacc, 0, 0, 0);
    }

    if (kq != 0) red[kq][dt][lane] = cacc;
    __syncthreads();
    if (kq == 0) {
        f32x4 r1 = red[1][dt][lane];
        f32x4 r2 = red[2][dt][lane];
        f32x4 r3 = red[3][dt][lane];
        cacc += r1 + r2 + r3;
        const int d = dt * 16 + (lane & 15);
        #pragma unroll
        for (int j = 0; j < 4; ++j) {
            int rowo = kgrp * 4 + j;              // D: row=(lane>>4)*4+j, col=lane&15
            V[(size_t)(row0 + rowo) * DOUT + d] = cacc[j];
        }
    }
}

// ---------------------------------------------------------------------------
extern "C" void kernel_launch(void* const* d_in, const int* in_sizes, int n_in,
                              void* d_out, int out_size, void* d_ws, size_t ws_size,
                              hipStream_t stream) {
    const float* X0   = (const float*)d_in[0];   // [4,1024,256]
    const float* tvec = (const float*)d_in[1];   // [4,1]
    const float* Wcw  = (const float*)d_in[2];   // [128,256]
    const float* Wcb  = (const float*)d_in[3];   // [128]
    const float* wq   = (const float*)d_in[4];   // [128]
    const float* A    = (const float*)d_in[5];   // [64,128,6]
    const float* Bp   = (const float*)d_in[6];   // [64,128,6]
    float*       V    = (float*)d_out;           // [4,1024,64]

    unsigned short* W2T = (unsigned short*)d_ws; // 64*1536*2 = 196608 B

    void* args[] = {(void*)&X0, (void*)&tvec, (void*)&Wcw, (void*)&Wcb,
                    (void*)&wq, (void*)&A, (void*)&Bp, (void*)&W2T, (void*)&V};
    hipLaunchCooperativeKernel((void*)k_all, dim3(NBLK), dim3(THR),
                               args, 0, stream);
}

// Round 4
// 22.127 us; speedup vs baseline: 3.4506x; 3.4506x over previous
//
#include <hip/hip_runtime.h>
#include <math.h>

#define NB   4
#define NS   1024
#define DIN  256
#define DOUT 64
#define NQ   128
#define NK   6
#define NROW (NB*NS)        // 4096
#define NF   (NQ*NK*2)      // 1536
#define ROWS 16
#define THR  1024

// ws layout (elements of unsigned short / bf16):
#define W2T_OFF 0                       // [DOUT][NF]      196608 B
#define WCH_OFF (DOUT*NF)               // [NQ][DIN] hi    65536 B
#define WCL_OFF (DOUT*NF + NQ*DIN)      // [NQ][DIN] lo    65536 B

typedef __attribute__((ext_vector_type(8))) short  short8;
typedef __attribute__((ext_vector_type(4))) short  short4v;
typedef __attribute__((ext_vector_type(4))) float  f32x4;

static __device__ __forceinline__ unsigned short f2bf(float x) {
    unsigned int u = __float_as_uint(x);
    u = (u + 0x7fffu + ((u >> 16) & 1u)) >> 16;   // RNE
    return (unsigned short)u;
}
static __device__ __forceinline__ float bf2f(unsigned short h) {
    return __uint_as_float(((unsigned int)h) << 16);
}

// ---------------------------------------------------------------------------
// K0: precompute (a) W2T[d][f] bf16, f=(k*2+c)*NQ+q  (c=0: A*cosB, c=1: A*sinB)
//     (b) hi/lo bf16 split of Wcw: Wch + Wcl  (x ~= hi + lo, ~16-bit mantissa)
// ---------------------------------------------------------------------------
__global__ __launch_bounds__(256) void k0_prep(const float* __restrict__ A,
                                               const float* __restrict__ Bp,
                                               const float* __restrict__ Wcw,
                                               unsigned short* __restrict__ ws) {
    int idx = blockIdx.x * 256 + threadIdx.x;
    if (idx < DOUT * NQ * NK) {
        int d   = idx / (NQ * NK);
        int rem = idx - d * (NQ * NK);
        int q   = rem / NK;
        int k   = rem - q * NK;
        float a = A[idx], bp = Bp[idx];
        float sb, cb;
        __sincosf(bp, &sb, &cb);
        ws[W2T_OFF + (size_t)d * NF + (k * 2 + 0) * NQ + q] = f2bf(a * cb);
        ws[W2T_OFF + (size_t)d * NF + (k * 2 + 1) * NQ + q] = f2bf(a * sb);
    } else {
        int j = idx - DOUT * NQ * NK;
        if (j < NQ * DIN) {
            float x = Wcw[j];
            unsigned short h = f2bf(x);
            unsigned short l = f2bf(x - bf2f(h));
            ws[WCH_OFF + j] = h;
            ws[WCL_OFF + j] = l;
        }
    }
}

// ---------------------------------------------------------------------------
// k_main: 256 blocks x 1024 thr (16 waves). LDS (64 KiB):
//  [0,8K)  XH[16][256] bf16 (row-xor)   [8K,16K) XL
//  [48K,56K) R2A [8 qt][64] f32x4   (phase-2 partial)
//  [0,48K)  F[16][1536] bf16 (row-xor)  -- overlays XH/XL after phase 2
//  [48K,64K) R4 [4 kq][4 dt][64] f32x4  -- overlays R2A after phase 3
// ---------------------------------------------------------------------------
__global__ __launch_bounds__(THR) void k_main(const float* __restrict__ X0,
                                              const float* __restrict__ tvec,
                                              const float* __restrict__ Wcb,
                                              const float* __restrict__ wq,
                                              const unsigned short* __restrict__ ws,
                                              float* __restrict__ V) {
    __shared__ char smem[65536];
    const int row0 = blockIdx.x * ROWS;
    const int tid  = threadIdx.x;
    const int lane = tid & 63;
    const int w    = tid >> 6;

    // ---- phase 1: stage X0 tile as hi/lo bf16 (row-xor swizzled) ----------
    {
        const int r  = tid >> 6;              // wave-uniform row
        const int kk = (tid & 63) * 4;        // 4 floats per thread
        float4 x = *(const float4*)(X0 + (size_t)(row0 + r) * DIN + kk);
        unsigned short h0 = f2bf(x.x), h1 = f2bf(x.y), h2 = f2bf(x.z), h3 = f2bf(x.w);
        short4v hv = {(short)h0, (short)h1, (short)h2, (short)h3};
        short4v lv = {(short)f2bf(x.x - bf2f(h0)), (short)f2bf(x.y - bf2f(h1)),
                      (short)f2bf(x.z - bf2f(h2)), (short)f2bf(x.w - bf2f(h3))};
        int off = (r * 512 + kk * 2) ^ ((r & 7) << 4);
        *(short4v*)(smem + off)        = hv;
        *(short4v*)(smem + 8192 + off) = lv;
    }
    __syncthreads();

    // ---- phase 2: angle[16][128] via MFMA, hi/lo error compensation -------
    // wave (qt = w&7 -> q-tile, kh = w>>3 -> K half of 128)
    const int qt  = w & 7;
    const int kh  = w >> 3;
    const int col = lane & 15;
    const int kg  = lane >> 4;
    const int q   = qt * 16 + col;

    f32x4 acc = {0.f, 0.f, 0.f, 0.f};
    {
        const short8* bh = (const short8*)(ws + WCH_OFF + (size_t)q * DIN + kh * 128 + kg * 8);
        const short8* bl = (const short8*)(ws + WCL_OFF + (size_t)q * DIN + kh * 128 + kg * 8);
        const int asw = (col & 7) << 4;
        #pragma unroll
        for (int s = 0; s < 4; ++s) {
            int k    = kh * 128 + s * 32 + kg * 8;
            int aoff = (col * 512 + k * 2) ^ asw;
            short8 ah  = *(const short8*)(smem + aoff);
            short8 al  = *(const short8*)(smem + 8192 + aoff);
            short8 bhv = bh[s * 4];
            short8 blv = bl[s * 4];
            acc = __builtin_amdgcn_mfma_f32_16x16x32_bf16(ah, bhv, acc, 0, 0, 0);
            acc = __builtin_amdgcn_mfma_f32_16x16x32_bf16(ah, blv, acc, 0, 0, 0);
            acc = __builtin_amdgcn_mfma_f32_16x16x32_bf16(al, bhv, acc, 0, 0, 0);
        }
    }
    f32x4* R2A = (f32x4*)(smem + 49152);
    if (kh == 1) R2A[qt * 64 + lane] = acc;
    __syncthreads();

    // ---- phase 3 (kh==0 waves): angles -> 12 bf16 features per angle ------
    if (kh == 0) {
        f32x4 p = R2A[qt * 64 + lane];
        const int   b    = row0 >> 10;
        const float bias = Wcb[q] + wq[q] * tvec[b];
        #pragma unroll
        for (int j = 0; j < 4; ++j) {
            float a = acc[j] + p[j] + bias;       // D: row = kg*4+j, col = q
            int   r = kg * 4 + j;
            int   sw = (r & 7) << 4;
            char* base = smem + r * (NF * 2);
            float s1, c1;
            __sincosf(a, &s1, &c1);
            float sk = s1, ck = c1;
            *(unsigned short*)(base + (((0 * NQ + q) * 2) ^ sw)) = f2bf(sk);
            *(unsigned short*)(base + (((1 * NQ + q) * 2) ^ sw)) = f2bf(ck);
            #pragma unroll
            for (int k = 1; k < NK; ++k) {
                float sn = sk * c1 + ck * s1;     // sin((k+1)a)
                float cn = ck * c1 - sk * s1;     // cos((k+1)a)
                *(unsigned short*)(base + ((((k * 2 + 0) * NQ + q) * 2) ^ sw)) = f2bf(sn);
                *(unsigned short*)(base + ((((k * 2 + 1) * NQ + q) * 2) ^ sw)) = f2bf(cn);
                sk = sn; ck = cn;
            }
        }
    }
    __syncthreads();

    // ---- phase 4: V[16][64] = F x W2T^T (waves: dt = w&3, kq = w>>2) ------
    const int dt  = w & 3;
    const int kq  = w >> 2;
    const int asw = (col & 7) << 4;
    f32x4 c2 = {0.f, 0.f, 0.f, 0.f};
    const unsigned short* wb = ws + W2T_OFF + (size_t)(dt * 16 + col) * NF + kg * 8;
    #pragma unroll 4
    for (int kk = 0; kk < 12; ++kk) {
        int k0   = kq * 384 + kk * 32;
        int aoff = (col * (NF * 2) + (k0 + kg * 8) * 2) ^ asw;
        short8 af = *(const short8*)(smem + aoff);
        short8 bf = *(const short8*)(wb + k0);
        c2 = __builtin_amdgcn_mfma_f32_16x16x32_bf16(af, bf, c2, 0, 0, 0);
    }
    f32x4* R4 = (f32x4*)(smem + 49152);
    if (kq != 0) R4[(kq * 4 + dt) * 64 + lane] = c2;
    __syncthreads();
    if (kq == 0) {
        c2 += R4[(1 * 4 + dt) * 64 + lane];
        c2 += R4[(2 * 4 + dt) * 64 + lane];
        c2 += R4[(3 * 4 + dt) * 64 + lane];
        const int d = dt * 16 + col;
        #pragma unroll
        for (int j = 0; j < 4; ++j)
            V[(size_t)(row0 + kg * 4 + j) * DOUT + d] = c2[j];
    }
}

// ---------------------------------------------------------------------------
extern "C" void kernel_launch(void* const* d_in, const int* in_sizes, int n_in,
                              void* d_out, int out_size, void* d_ws, size_t ws_size,
                              hipStream_t stream) {
    const float* X0   = (const float*)d_in[0];   // [4,1024,256]
    const float* tvec = (const float*)d_in[1];   // [4,1]
    const float* Wcw  = (const float*)d_in[2];   // [128,256]
    const float* Wcb  = (const float*)d_in[3];   // [128]
    const float* wq   = (const float*)d_in[4];   // [128]
    const float* A    = (const float*)d_in[5];   // [64,128,6]
    const float* Bp   = (const float*)d_in[6];   // [64,128,6]
    float*       V    = (float*)d_out;           // [4,1024,64]

    unsigned short* ws = (unsigned short*)d_ws;  // W2T + Wch + Wcl = 327680 B

    k0_prep<<<(DOUT * NQ * NK + NQ * DIN + 255) / 256, 256, 0, stream>>>(A, Bp, Wcw, ws);
    k_main <<<NROW / ROWS, THR, 0, stream>>>(X0, tvec, Wcb, wq, ws, V);
}